// Round 3
// baseline (2829.965 us; speedup 1.0000x reference)
//
#include <hip/hip_runtime.h>
#include <hip/hip_bf16.h>

#define C_DIM 128
#define N_WIN 98
#define M_TOK 200704   // 8*8*56*56
#define B_WIN 2048

struct __align__(8) bf16x4 { __hip_bfloat16 h[4]; };

// token index map used by BOTH gather (LN1) and scatter (proj epilogue):
// row = widx*98 + n  ->  flat spatial token index in the original layout
__device__ __forceinline__ int token_spatial_index(int row) {
    int widx = row / 98;
    int n = row - widx * 98;
    int b   = widx >> 8;          // / 256
    int rem = widx & 255;
    int dI = rem >> 6;            // D/2 = 4
    int hI = (rem >> 3) & 7;      // H/7 = 8
    int wI = rem & 7;             // W/7 = 8
    int dw = n / 49;
    int r49 = n - dw * 49;
    int hw = r49 / 7;
    int ww = r49 - hw * 7;
    int d = dI * 2 + dw;          // shifted-frame coords
    int h = hI * 7 + hw;
    int w = wI * 7 + ww;
    d = (d + 1) & 7;              // shifted[i] = orig[(i+1)%8]  (roll -1)
    h += 3; if (h >= 56) h -= 56; // roll -3
    w += 3; if (w >= 56) w -= 56;
    return ((b * 8 + d) * 56 + h) * 56 + w;
}

// ---------------- Kernel 1: LN1 + window gather + QKV GEMM ----------------
__global__ __launch_bounds__(256) void ln1_qkv_kernel(
    const float* __restrict__ x,
    const float* __restrict__ g1,
    const float* __restrict__ b1,
    const float* __restrict__ qkv_w,   // (384,128)
    const float* __restrict__ qkv_b,   // (384,)
    __hip_bfloat16* __restrict__ qkv_out)       // (200704,384) bf16 scratch
{
    __shared__ float At[128][68];   // [k][r], padded
    __shared__ float Wt[128][68];   // [k][c]
    __shared__ int   srcL[64];
    __shared__ float meanL[64], rstdL[64];

    const int tid = threadIdx.x;
    const int rowbase = blockIdx.x * 64;

    if (tid < 64) srcL[tid] = token_spatial_index(rowbase + tid);
    __syncthreads();

    // load raw x tile, transposed
    #pragma unroll
    for (int i = 0; i < 32; ++i) {
        int e = tid + i * 256;
        int r = e >> 7, k = e & 127;
        At[k][r] = x[(size_t)srcL[r] * 128 + k];
    }
    __syncthreads();
    if (tid < 64) {
        float s = 0.f, ss = 0.f;
        #pragma unroll 8
        for (int k = 0; k < 128; ++k) { float v = At[k][tid]; s += v; ss += v * v; }
        float m = s * (1.f / 128.f);
        float var = ss * (1.f / 128.f) - m * m;
        meanL[tid] = m;
        rstdL[tid] = rsqrtf(var + 1e-5f);
    }
    __syncthreads();
    #pragma unroll
    for (int i = 0; i < 32; ++i) {
        int e = tid + i * 256;
        int k = e >> 6, r = e & 63;
        At[k][r] = (At[k][r] - meanL[r]) * rstdL[r] * g1[k] + b1[k];
    }
    __syncthreads();

    const int tr = tid >> 4, tc = tid & 15;
    const int tr4 = tr * 4, tc4 = tc * 4;

    for (int nt = 0; nt < 6; ++nt) {
        #pragma unroll
        for (int i = 0; i < 32; ++i) {
            int e = tid + i * 256;
            int c = e >> 7, k = e & 127;
            Wt[k][c] = qkv_w[(size_t)(nt * 64 + c) * 128 + k];
        }
        __syncthreads();
        float acc[4][4] = {};
        #pragma unroll 8
        for (int k = 0; k < 128; ++k) {
            float4 a = *(const float4*)(&At[k][tr4]);
            float4 w = *(const float4*)(&Wt[k][tc4]);
            acc[0][0] += a.x * w.x; acc[0][1] += a.x * w.y; acc[0][2] += a.x * w.z; acc[0][3] += a.x * w.w;
            acc[1][0] += a.y * w.x; acc[1][1] += a.y * w.y; acc[1][2] += a.y * w.z; acc[1][3] += a.y * w.w;
            acc[2][0] += a.z * w.x; acc[2][1] += a.z * w.y; acc[2][2] += a.z * w.z; acc[2][3] += a.z * w.w;
            acc[3][0] += a.w * w.x; acc[3][1] += a.w * w.y; acc[3][2] += a.w * w.z; acc[3][3] += a.w * w.w;
        }
        __syncthreads();   // protect Wt refill next iteration
        int gcol = nt * 64 + tc4;
        float bs0 = qkv_b[gcol + 0];
        float bs1 = qkv_b[gcol + 1];
        float bs2 = qkv_b[gcol + 2];
        float bs3 = qkv_b[gcol + 3];
        #pragma unroll
        for (int i2 = 0; i2 < 4; ++i2) {
            int grow = rowbase + tr4 + i2;
            bf16x4 pk;
            pk.h[0] = __float2bfloat16(acc[i2][0] + bs0);
            pk.h[1] = __float2bfloat16(acc[i2][1] + bs1);
            pk.h[2] = __float2bfloat16(acc[i2][2] + bs2);
            pk.h[3] = __float2bfloat16(acc[i2][3] + bs3);
            *(bf16x4*)(qkv_out + (size_t)grow * 384 + gcol) = pk;
        }
    }
}

// ---------------- Kernel 2: attention per (window, head) ----------------
__global__ __launch_bounds__(256) void attn_kernel(
    __hip_bfloat16* __restrict__ qkv,           // (200704,384); out overwrites q-slice
    const float* __restrict__ mask,             // (256,98,98)
    const float* __restrict__ rel_bias)         // (507,4)
{
    __shared__ float q[98][33], kk[98][33], vv[98][33];
    __shared__ float sc[98][99];

    const int tid = threadIdx.x;
    const int widx = blockIdx.x >> 2;
    const int head = blockIdx.x & 3;
    const size_t base = (size_t)widx * 98 * 384;
    const int co = head * 32;
    const float scale = 0.17677669529663687f;   // 32^-0.5

    for (int e = tid; e < 98 * 32; e += 256) {
        int n = e >> 5, c = e & 31;
        size_t roff = base + (size_t)n * 384;
        q[n][c]  = __bfloat162float(qkv[roff + co + c]) * scale;
        kk[n][c] = __bfloat162float(qkv[roff + 128 + co + c]);
        vv[n][c] = __bfloat162float(qkv[roff + 256 + co + c]);
    }
    __syncthreads();

    const int wloc = widx & 255;
    const float* mrow = mask + (size_t)wloc * 9604;
    for (int e = tid; e < 9604; e += 256) {
        int n = e / 98, m = e - n * 98;
        float s = 0.f;
        #pragma unroll 8
        for (int c = 0; c < 32; ++c) s += q[n][c] * kk[m][c];
        int d1 = n / 49, r1 = n - d1 * 49, h1 = r1 / 7, w1 = r1 - h1 * 7;
        int d2 = m / 49, r2 = m - d2 * 49, h2 = r2 / 7, w2 = r2 - h2 * 7;
        int bidx = (d1 - d2 + 1) * 169 + (h1 - h2 + 6) * 13 + (w1 - w2 + 6);
        s += rel_bias[bidx * 4 + head];
        s += mrow[e];
        sc[n][m] = s;
    }
    __syncthreads();

    if (tid < 98) {
        float mx = -1e30f;
        for (int m2 = 0; m2 < 98; ++m2) mx = fmaxf(mx, sc[tid][m2]);
        float sum = 0.f;
        for (int m2 = 0; m2 < 98; ++m2) {
            float e2 = expf(sc[tid][m2] - mx);
            sc[tid][m2] = e2; sum += e2;
        }
        float inv = 1.f / sum;
        for (int m2 = 0; m2 < 98; ++m2) sc[tid][m2] *= inv;
    }
    __syncthreads();

    for (int e = tid; e < 98 * 32; e += 256) {
        int n = e >> 5, c = e & 31;
        float o = 0.f;
        #pragma unroll 7
        for (int m2 = 0; m2 < 98; ++m2) o += sc[n][m2] * vv[m2][c];
        qkv[base + (size_t)n * 384 + co + c] = __float2bfloat16(o);  // q-slice reuse
    }
}

// ---------------- Kernel 3: proj GEMM + window-reverse scatter + residual ----------------
__global__ __launch_bounds__(256) void proj_kernel(
    const __hip_bfloat16* __restrict__ attn,    // qkv buffer, cols 0..127 hold attn out
    const float* __restrict__ proj_w,           // (128,128)
    const float* __restrict__ proj_b,
    const float* __restrict__ x,
    float* __restrict__ x2)
{
    __shared__ float At[128][68];
    __shared__ float Wt[128][68];
    __shared__ int dstL[64];

    const int tid = threadIdx.x;
    const int rowbase = blockIdx.x * 64;
    if (tid < 64) dstL[tid] = token_spatial_index(rowbase + tid);
    __syncthreads();

    #pragma unroll
    for (int i = 0; i < 32; ++i) {
        int e = tid + i * 256;
        int r = e >> 7, k = e & 127;
        At[k][r] = __bfloat162float(attn[(size_t)(rowbase + r) * 384 + k]);
    }

    const int tr = tid >> 4, tc = tid & 15;
    const int tr4 = tr * 4, tc4 = tc * 4;

    for (int nt = 0; nt < 2; ++nt) {
        #pragma unroll
        for (int i = 0; i < 32; ++i) {
            int e = tid + i * 256;
            int c = e >> 7, k = e & 127;
            Wt[k][c] = proj_w[(size_t)(nt * 64 + c) * 128 + k];
        }
        __syncthreads();
        float acc[4][4] = {};
        #pragma unroll 8
        for (int k = 0; k < 128; ++k) {
            float4 a = *(const float4*)(&At[k][tr4]);
            float4 w = *(const float4*)(&Wt[k][tc4]);
            acc[0][0] += a.x * w.x; acc[0][1] += a.x * w.y; acc[0][2] += a.x * w.z; acc[0][3] += a.x * w.w;
            acc[1][0] += a.y * w.x; acc[1][1] += a.y * w.y; acc[1][2] += a.y * w.z; acc[1][3] += a.y * w.w;
            acc[2][0] += a.z * w.x; acc[2][1] += a.z * w.y; acc[2][2] += a.z * w.z; acc[2][3] += a.z * w.w;
            acc[3][0] += a.w * w.x; acc[3][1] += a.w * w.y; acc[3][2] += a.w * w.z; acc[3][3] += a.w * w.w;
        }
        __syncthreads();
        int gcol = nt * 64 + tc4;
        float bs0 = proj_b[gcol + 0];
        float bs1 = proj_b[gcol + 1];
        float bs2 = proj_b[gcol + 2];
        float bs3 = proj_b[gcol + 3];
        #pragma unroll
        for (int i2 = 0; i2 < 4; ++i2) {
            int dst = dstL[tr4 + i2];
            size_t off = (size_t)dst * 128 + gcol;
            float4 xr = *(const float4*)(x + off);
            float4 res;
            res.x = acc[i2][0] + bs0 + xr.x;
            res.y = acc[i2][1] + bs1 + xr.y;
            res.z = acc[i2][2] + bs2 + xr.z;
            res.w = acc[i2][3] + bs3 + xr.w;
            *(float4*)(x2 + off) = res;
        }
    }
}

// ---------------- Kernel 4: LN2 + fc1 + GELU + fc2 + residual ----------------
__global__ __launch_bounds__(256) void mlp_kernel(
    const float* __restrict__ x2,
    const float* __restrict__ g2,
    const float* __restrict__ b2,
    const float* __restrict__ fc1_w,   // (512,128)
    const float* __restrict__ fc1_b,
    const float* __restrict__ fc2_w,   // (128,512)
    const float* __restrict__ fc2_b,
    float* __restrict__ out)
{
    __shared__ float raw[16][129];
    __shared__ float At[128][20];    // normalized, transposed [k][r]
    __shared__ float Ht[512][20];    // hidden, transposed [k][r]
    __shared__ float meanL[16], rstdL[16];

    const int tid = threadIdx.x;
    const int rowbase = blockIdx.x * 16;

    for (int e = tid; e < 16 * 128; e += 256) {
        int r = e >> 7, k = e & 127;
        raw[r][k] = x2[(size_t)(rowbase + r) * 128 + k];
    }
    __syncthreads();
    if (tid < 16) {
        float s = 0.f, ss = 0.f;
        #pragma unroll 8
        for (int k = 0; k < 128; ++k) { float v = raw[tid][k]; s += v; ss += v * v; }
        float m = s * (1.f / 128.f);
        float var = ss * (1.f / 128.f) - m * m;
        meanL[tid] = m;
        rstdL[tid] = rsqrtf(var + 1e-5f);
    }
    __syncthreads();
    for (int e = tid; e < 16 * 128; e += 256) {
        int k = e >> 4, r = e & 15;
        At[k][r] = (raw[r][k] - meanL[r]) * rstdL[r] * g2[k] + b2[k];
    }
    __syncthreads();

    // fc1 + exact GELU: each thread owns cols tid and tid+256
    #pragma unroll
    for (int half = 0; half < 2; ++half) {
        int col = tid + half * 256;
        const float* wrow = fc1_w + (size_t)col * 128;
        float acc[16] = {};
        #pragma unroll 4
        for (int k = 0; k < 128; ++k) {
            float w = wrow[k];
            float4 a0 = *(const float4*)(&At[k][0]);
            float4 a1 = *(const float4*)(&At[k][4]);
            float4 a2 = *(const float4*)(&At[k][8]);
            float4 a3 = *(const float4*)(&At[k][12]);
            acc[0] += w * a0.x; acc[1] += w * a0.y; acc[2]  += w * a0.z; acc[3]  += w * a0.w;
            acc[4] += w * a1.x; acc[5] += w * a1.y; acc[6]  += w * a1.z; acc[7]  += w * a1.w;
            acc[8] += w * a2.x; acc[9] += w * a2.y; acc[10] += w * a2.z; acc[11] += w * a2.w;
            acc[12]+= w * a3.x; acc[13]+= w * a3.y; acc[14] += w * a3.z; acc[15] += w * a3.w;
        }
        float bb = fc1_b[col];
        float hv[16];
        #pragma unroll
        for (int r = 0; r < 16; ++r) {
            float v = acc[r] + bb;
            hv[r] = 0.5f * v * (1.f + erff(v * 0.70710678118654752f));
        }
        #pragma unroll
        for (int r = 0; r < 16; ++r) Ht[col][r] = hv[r];
    }
    __syncthreads();

    // fc2 + residual: col = tid&127, rows (tid>>7)*8 .. +8
    {
        int col = tid & 127;
        int r0 = (tid >> 7) * 8;
        const float* wrow = fc2_w + (size_t)col * 512;
        float acc[8] = {};
        #pragma unroll 4
        for (int k = 0; k < 512; ++k) {
            float w = wrow[k];
            float4 h0 = *(const float4*)(&Ht[k][r0]);
            float4 h1 = *(const float4*)(&Ht[k][r0 + 4]);
            acc[0] += w * h0.x; acc[1] += w * h0.y; acc[2] += w * h0.z; acc[3] += w * h0.w;
            acc[4] += w * h1.x; acc[5] += w * h1.y; acc[6] += w * h1.z; acc[7] += w * h1.w;
        }
        float bb = fc2_b[col];
        #pragma unroll
        for (int i2 = 0; i2 < 8; ++i2) {
            int r = r0 + i2;
            float v = raw[r][col] + acc[i2] + bb;
            out[(size_t)(rowbase + r) * 128 + col] = v;
        }
    }
}

extern "C" void kernel_launch(void* const* d_in, const int* in_sizes, int n_in,
                              void* d_out, int out_size, void* d_ws, size_t ws_size,
                              hipStream_t stream) {
    const float* x        = (const float*)d_in[0];
    const float* mask     = (const float*)d_in[1];
    const float* n1g      = (const float*)d_in[2];
    const float* n1b      = (const float*)d_in[3];
    const float* qkv_w    = (const float*)d_in[4];
    const float* qkv_b    = (const float*)d_in[5];
    const float* rel_bias = (const float*)d_in[6];
    const float* proj_w   = (const float*)d_in[7];
    const float* proj_b   = (const float*)d_in[8];
    const float* n2g      = (const float*)d_in[9];
    const float* n2b      = (const float*)d_in[10];
    const float* fc1_w    = (const float*)d_in[11];
    const float* fc1_b    = (const float*)d_in[12];
    const float* fc2_w    = (const float*)d_in[13];
    const float* fc2_b    = (const float*)d_in[14];
    float* out = (float*)d_out;

    __hip_bfloat16* qkv = (__hip_bfloat16*)d_ws;                       // 200704*384*2 = 154,140,672 B
    float* x2 = (float*)((char*)d_ws + 154140672);                     // 200704*128*4 = 102,760,448 B

    ln1_qkv_kernel<<<3136, 256, 0, stream>>>(x, n1g, n1b, qkv_w, qkv_b, qkv);
    attn_kernel<<<8192, 256, 0, stream>>>(qkv, mask, rel_bias);
    proj_kernel<<<3136, 256, 0, stream>>>(qkv, proj_w, proj_b, x, x2);
    mlp_kernel<<<12544, 256, 0, stream>>>(x2, n2g, n2b, fc1_w, fc1_b, fc2_w, fc2_b, out);
}

// Round 4
// 1798.439 us; speedup vs baseline: 1.5736x; 1.5736x over previous
//
#include <hip/hip_runtime.h>
#include <hip/hip_bf16.h>

#define C_DIM 128
#define N_WIN 98
#define M_TOK 200704   // 8*8*56*56
#define B_WIN 2048

struct __align__(8) bf16x4 { __hip_bfloat16 h[4]; };

typedef __attribute__((ext_vector_type(8))) short bf16x8_t;   // 8 bf16 = 4 VGPRs
typedef __attribute__((ext_vector_type(4))) float f32x4_t;

// token index map used by BOTH gather (LN1) and scatter (proj epilogue):
// row = widx*98 + n  ->  flat spatial token index in the original layout
__device__ __forceinline__ int token_spatial_index(int row) {
    int widx = row / 98;
    int n = row - widx * 98;
    int b   = widx >> 8;          // / 256
    int rem = widx & 255;
    int dI = rem >> 6;            // D/2 = 4
    int hI = (rem >> 3) & 7;      // H/7 = 8
    int wI = rem & 7;             // W/7 = 8
    int dw = n / 49;
    int r49 = n - dw * 49;
    int hw = r49 / 7;
    int ww = r49 - hw * 7;
    int d = dI * 2 + dw;          // shifted-frame coords
    int h = hI * 7 + hw;
    int w = wI * 7 + ww;
    d = (d + 1) & 7;              // shifted[i] = orig[(i+1)%8]  (roll -1)
    h += 3; if (h >= 56) h -= 56; // roll -3
    w += 3; if (w >= 56) w -= 56;
    return ((b * 8 + d) * 56 + h) * 56 + w;
}

// ---------------- Kernel 1: LN1 + window gather + QKV GEMM ----------------
__global__ __launch_bounds__(256) void ln1_qkv_kernel(
    const float* __restrict__ x,
    const float* __restrict__ g1,
    const float* __restrict__ b1,
    const float* __restrict__ qkv_w,   // (384,128)
    const float* __restrict__ qkv_b,   // (384,)
    __hip_bfloat16* __restrict__ qkv_out)       // (200704,384) bf16 scratch
{
    __shared__ float At[128][68];   // [k][r], padded
    __shared__ float Wt[128][68];   // [k][c]
    __shared__ int   srcL[64];
    __shared__ float meanL[64], rstdL[64];

    const int tid = threadIdx.x;
    const int rowbase = blockIdx.x * 64;

    if (tid < 64) srcL[tid] = token_spatial_index(rowbase + tid);
    __syncthreads();

    #pragma unroll
    for (int i = 0; i < 32; ++i) {
        int e = tid + i * 256;
        int r = e >> 7, k = e & 127;
        At[k][r] = x[(size_t)srcL[r] * 128 + k];
    }
    __syncthreads();
    if (tid < 64) {
        float s = 0.f, ss = 0.f;
        #pragma unroll 8
        for (int k = 0; k < 128; ++k) { float v = At[k][tid]; s += v; ss += v * v; }
        float m = s * (1.f / 128.f);
        float var = ss * (1.f / 128.f) - m * m;
        meanL[tid] = m;
        rstdL[tid] = rsqrtf(var + 1e-5f);
    }
    __syncthreads();
    #pragma unroll
    for (int i = 0; i < 32; ++i) {
        int e = tid + i * 256;
        int k = e >> 6, r = e & 63;
        At[k][r] = (At[k][r] - meanL[r]) * rstdL[r] * g1[k] + b1[k];
    }
    __syncthreads();

    const int tr = tid >> 4, tc = tid & 15;
    const int tr4 = tr * 4, tc4 = tc * 4;

    for (int nt = 0; nt < 6; ++nt) {
        #pragma unroll
        for (int i = 0; i < 32; ++i) {
            int e = tid + i * 256;
            int c = e >> 7, k = e & 127;
            Wt[k][c] = qkv_w[(size_t)(nt * 64 + c) * 128 + k];
        }
        __syncthreads();
        float acc[4][4] = {};
        #pragma unroll 8
        for (int k = 0; k < 128; ++k) {
            float4 a = *(const float4*)(&At[k][tr4]);
            float4 w = *(const float4*)(&Wt[k][tc4]);
            acc[0][0] += a.x * w.x; acc[0][1] += a.x * w.y; acc[0][2] += a.x * w.z; acc[0][3] += a.x * w.w;
            acc[1][0] += a.y * w.x; acc[1][1] += a.y * w.y; acc[1][2] += a.y * w.z; acc[1][3] += a.y * w.w;
            acc[2][0] += a.z * w.x; acc[2][1] += a.z * w.y; acc[2][2] += a.z * w.z; acc[2][3] += a.z * w.w;
            acc[3][0] += a.w * w.x; acc[3][1] += a.w * w.y; acc[3][2] += a.w * w.z; acc[3][3] += a.w * w.w;
        }
        __syncthreads();
        int gcol = nt * 64 + tc4;
        float bs0 = qkv_b[gcol + 0];
        float bs1 = qkv_b[gcol + 1];
        float bs2 = qkv_b[gcol + 2];
        float bs3 = qkv_b[gcol + 3];
        #pragma unroll
        for (int i2 = 0; i2 < 4; ++i2) {
            int grow = rowbase + tr4 + i2;
            bf16x4 pk;
            pk.h[0] = __float2bfloat16(acc[i2][0] + bs0);
            pk.h[1] = __float2bfloat16(acc[i2][1] + bs1);
            pk.h[2] = __float2bfloat16(acc[i2][2] + bs2);
            pk.h[3] = __float2bfloat16(acc[i2][3] + bs3);
            *(bf16x4*)(qkv_out + (size_t)grow * 384 + gcol) = pk;
        }
    }
}

// ---------------- Kernel 2: attention per (window, head) ----------------
__global__ __launch_bounds__(256) void attn_kernel(
    __hip_bfloat16* __restrict__ qkv,           // (200704,384); out overwrites q-slice
    const float* __restrict__ mask,             // (256,98,98)
    const float* __restrict__ rel_bias)         // (507,4)
{
    __shared__ float q[98][33], kk[98][33], vv[98][33];
    __shared__ float sc[98][99];

    const int tid = threadIdx.x;
    const int widx = blockIdx.x >> 2;
    const int head = blockIdx.x & 3;
    const size_t base = (size_t)widx * 98 * 384;
    const int co = head * 32;
    const float scale = 0.17677669529663687f;   // 32^-0.5

    for (int e = tid; e < 98 * 32; e += 256) {
        int n = e >> 5, c = e & 31;
        size_t roff = base + (size_t)n * 384;
        q[n][c]  = __bfloat162float(qkv[roff + co + c]) * scale;
        kk[n][c] = __bfloat162float(qkv[roff + 128 + co + c]);
        vv[n][c] = __bfloat162float(qkv[roff + 256 + co + c]);
    }
    __syncthreads();

    const int wloc = widx & 255;
    const float* mrow = mask + (size_t)wloc * 9604;
    for (int e = tid; e < 9604; e += 256) {
        int n = e / 98, m = e - n * 98;
        float s = 0.f;
        #pragma unroll 8
        for (int c = 0; c < 32; ++c) s += q[n][c] * kk[m][c];
        int d1 = n / 49, r1 = n - d1 * 49, h1 = r1 / 7, w1 = r1 - h1 * 7;
        int d2 = m / 49, r2 = m - d2 * 49, h2 = r2 / 7, w2 = r2 - h2 * 7;
        int bidx = (d1 - d2 + 1) * 169 + (h1 - h2 + 6) * 13 + (w1 - w2 + 6);
        s += rel_bias[bidx * 4 + head];
        s += mrow[e];
        sc[n][m] = s;
    }
    __syncthreads();

    if (tid < 98) {
        float mx = -1e30f;
        for (int m2 = 0; m2 < 98; ++m2) mx = fmaxf(mx, sc[tid][m2]);
        float sum = 0.f;
        for (int m2 = 0; m2 < 98; ++m2) {
            float e2 = expf(sc[tid][m2] - mx);
            sc[tid][m2] = e2; sum += e2;
        }
        float inv = 1.f / sum;
        for (int m2 = 0; m2 < 98; ++m2) sc[tid][m2] *= inv;
    }
    __syncthreads();

    for (int e = tid; e < 98 * 32; e += 256) {
        int n = e >> 5, c = e & 31;
        float o = 0.f;
        #pragma unroll 7
        for (int m2 = 0; m2 < 98; ++m2) o += sc[n][m2] * vv[m2][c];
        qkv[base + (size_t)n * 384 + co + c] = __float2bfloat16(o);  // q-slice reuse
    }
}

// ---------------- Kernel 3: proj GEMM + window-reverse scatter + residual ----------------
__global__ __launch_bounds__(256) void proj_kernel(
    const __hip_bfloat16* __restrict__ attn,    // qkv buffer, cols 0..127 hold attn out
    const float* __restrict__ proj_w,           // (128,128)
    const float* __restrict__ proj_b,
    const float* __restrict__ x,
    float* __restrict__ x2)
{
    __shared__ float At[128][68];
    __shared__ float Wt[128][68];
    __shared__ int dstL[64];

    const int tid = threadIdx.x;
    const int rowbase = blockIdx.x * 64;
    if (tid < 64) dstL[tid] = token_spatial_index(rowbase + tid);
    __syncthreads();

    #pragma unroll
    for (int i = 0; i < 32; ++i) {
        int e = tid + i * 256;
        int r = e >> 7, k = e & 127;
        At[k][r] = __bfloat162float(attn[(size_t)(rowbase + r) * 384 + k]);
    }

    const int tr = tid >> 4, tc = tid & 15;
    const int tr4 = tr * 4, tc4 = tc * 4;

    for (int nt = 0; nt < 2; ++nt) {
        #pragma unroll
        for (int i = 0; i < 32; ++i) {
            int e = tid + i * 256;
            int c = e >> 7, k = e & 127;
            Wt[k][c] = proj_w[(size_t)(nt * 64 + c) * 128 + k];
        }
        __syncthreads();
        float acc[4][4] = {};
        #pragma unroll 8
        for (int k = 0; k < 128; ++k) {
            float4 a = *(const float4*)(&At[k][tr4]);
            float4 w = *(const float4*)(&Wt[k][tc4]);
            acc[0][0] += a.x * w.x; acc[0][1] += a.x * w.y; acc[0][2] += a.x * w.z; acc[0][3] += a.x * w.w;
            acc[1][0] += a.y * w.x; acc[1][1] += a.y * w.y; acc[1][2] += a.y * w.z; acc[1][3] += a.y * w.w;
            acc[2][0] += a.z * w.x; acc[2][1] += a.z * w.y; acc[2][2] += a.z * w.z; acc[2][3] += a.z * w.w;
            acc[3][0] += a.w * w.x; acc[3][1] += a.w * w.y; acc[3][2] += a.w * w.z; acc[3][3] += a.w * w.w;
        }
        __syncthreads();
        int gcol = nt * 64 + tc4;
        float bs0 = proj_b[gcol + 0];
        float bs1 = proj_b[gcol + 1];
        float bs2 = proj_b[gcol + 2];
        float bs3 = proj_b[gcol + 3];
        #pragma unroll
        for (int i2 = 0; i2 < 4; ++i2) {
            int dst = dstL[tr4 + i2];
            size_t off = (size_t)dst * 128 + gcol;
            float4 xr = *(const float4*)(x + off);
            float4 res;
            res.x = acc[i2][0] + bs0 + xr.x;
            res.y = acc[i2][1] + bs1 + xr.y;
            res.z = acc[i2][2] + bs2 + xr.z;
            res.w = acc[i2][3] + bs3 + xr.w;
            *(float4*)(x2 + off) = res;
        }
    }
}

// ---------------- Kernel 3.5: convert MLP weights fp32 -> bf16 (into dead qkv region) ----------------
__global__ __launch_bounds__(256) void prep_weights(
    const float* __restrict__ fc1_w,   // (512,128) = 65536
    const float* __restrict__ fc2_w,   // (128,512) = 65536
    __hip_bfloat16* __restrict__ wb)   // [0..65535]=fc1, [65536..131071]=fc2
{
    int i = blockIdx.x * 256 + threadIdx.x;
    if (i < 65536)       wb[i] = __float2bfloat16(fc1_w[i]);
    else if (i < 131072) wb[i] = __float2bfloat16(fc2_w[i - 65536]);
}

// ---------------- Kernel 4: LN2 + fc1 + GELU + fc2 + residual (MFMA) ----------------
// 32 rows/block, 4 waves. mfma_f32_16x16x32_bf16:
//   A frag: lane holds A[m=lane&15][k=quad*8+j]   (row-major, 8 contiguous bf16 = b128)
//   B frag: lane holds W[n=lane&15][k=quad*8+j]   (weights are (N,K) row-major = m97 gemm_bt layout)
//   C/D   : col=lane&15, row=quad*4+reg           (m89-verified)
__global__ __launch_bounds__(256) void mlp_mfma_kernel(
    const float* __restrict__ x2,
    const float* __restrict__ g2,
    const float* __restrict__ b2,
    const __hip_bfloat16* __restrict__ fc1_wb,  // (512,128) bf16
    const __hip_bfloat16* __restrict__ fc2_wb,  // (128,512) bf16
    const float* __restrict__ fc1_b,
    const float* __restrict__ fc2_b,
    float* __restrict__ out)
{
    __shared__ float raw[32][132];                         // 16896 B (residual + LN input)
    __shared__ __align__(16) __hip_bfloat16 Abf[32][136];  // 8704 B  (LN output, bf16)
    __shared__ __align__(16) __hip_bfloat16 Hbf[32][520];  // 33280 B (hidden, bf16)
    __shared__ float meanL[32], rstdL[32];

    const int tid  = threadIdx.x;
    const int lane = tid & 63;
    const int wv   = tid >> 6;
    const int rowbase = blockIdx.x * 32;

    // ---- load x2 tile (float4, coalesced) ----
    #pragma unroll
    for (int i = 0; i < 4; ++i) {
        int idx = tid + i * 256;            // 1024 float4 = 32*128 floats
        int r = idx >> 5, c4 = idx & 31;
        float4 v = *(const float4*)(x2 + (size_t)(rowbase + r) * 128 + c4 * 4);
        *(float4*)(&raw[r][c4 * 4]) = v;
    }
    __syncthreads();

    // ---- LN stats: 8 threads per row, shfl reduce ----
    {
        int r = tid >> 3, part = tid & 7;
        float s = 0.f, ss = 0.f;
        #pragma unroll
        for (int j = 0; j < 16; ++j) {
            float v = raw[r][part * 16 + j];
            s += v; ss += v * v;
        }
        s  += __shfl_xor(s, 1);  ss += __shfl_xor(ss, 1);
        s  += __shfl_xor(s, 2);  ss += __shfl_xor(ss, 2);
        s  += __shfl_xor(s, 4);  ss += __shfl_xor(ss, 4);
        if (part == 0) {
            float m = s * (1.f / 128.f);
            float var = ss * (1.f / 128.f) - m * m;
            meanL[r] = m;
            rstdL[r] = rsqrtf(var + 1e-5f);
        }
    }
    __syncthreads();

    // ---- normalize -> Abf (bf16) ----
    #pragma unroll
    for (int i = 0; i < 16; ++i) {
        int e = tid + i * 256;
        int r = e >> 7, k = e & 127;
        float v = (raw[r][k] - meanL[r]) * rstdL[r] * g2[k] + b2[k];
        Abf[r][k] = __float2bfloat16(v);
    }
    __syncthreads();

    const int rw    = (wv & 1) * 16;        // wave's row offset
    const int chalf = (wv >> 1) * 256;      // wave's fc1 col half
    const int lm    = lane & 15;
    const int quad  = lane >> 4;

    // ---- fc1 (K=128) + GELU -> Hbf ----
    {
        bf16x8_t afr[4];
        #pragma unroll
        for (int s = 0; s < 4; ++s)
            afr[s] = *(const bf16x8_t*)(&Abf[rw + lm][s * 32 + quad * 8]);

        for (int ct = 0; ct < 16; ++ct) {
            int ccol = chalf + ct * 16 + lm;
            const __hip_bfloat16* wp = fc1_wb + (size_t)ccol * 128 + quad * 8;
            f32x4_t acc = {0.f, 0.f, 0.f, 0.f};
            #pragma unroll
            for (int s = 0; s < 4; ++s) {
                bf16x8_t bfr = *(const bf16x8_t*)(wp + s * 32);
                acc = __builtin_amdgcn_mfma_f32_16x16x32_bf16(afr[s], bfr, acc, 0, 0, 0);
            }
            float bb = fc1_b[ccol];
            #pragma unroll
            for (int rg = 0; rg < 4; ++rg) {
                float v = acc[rg] + bb;
                v = 0.5f * v * (1.f + erff(v * 0.70710678118654752f));
                Hbf[rw + quad * 4 + rg][ccol] = __float2bfloat16(v);
            }
        }
    }
    __syncthreads();

    // ---- fc2 (K=512) + bias + residual -> out ----
    {
        const int cq = (wv >> 1) * 64;      // wave's fc2 col quarter
        bf16x8_t hfr[16];
        #pragma unroll
        for (int s = 0; s < 16; ++s)
            hfr[s] = *(const bf16x8_t*)(&Hbf[rw + lm][s * 32 + quad * 8]);

        #pragma unroll
        for (int ct = 0; ct < 4; ++ct) {
            int ccol = cq + ct * 16 + lm;
            const __hip_bfloat16* wp = fc2_wb + (size_t)ccol * 512 + quad * 8;
            f32x4_t acc = {0.f, 0.f, 0.f, 0.f};
            #pragma unroll
            for (int s = 0; s < 16; ++s) {
                bf16x8_t bfr = *(const bf16x8_t*)(wp + s * 32);
                acc = __builtin_amdgcn_mfma_f32_16x16x32_bf16(hfr[s], bfr, acc, 0, 0, 0);
            }
            float bb = fc2_b[ccol];
            #pragma unroll
            for (int rg = 0; rg < 4; ++rg) {
                int rr = rw + quad * 4 + rg;
                out[(size_t)(rowbase + rr) * 128 + ccol] = acc[rg] + bb + raw[rr][ccol];
            }
        }
    }
}

extern "C" void kernel_launch(void* const* d_in, const int* in_sizes, int n_in,
                              void* d_out, int out_size, void* d_ws, size_t ws_size,
                              hipStream_t stream) {
    const float* x        = (const float*)d_in[0];
    const float* mask     = (const float*)d_in[1];
    const float* n1g      = (const float*)d_in[2];
    const float* n1b      = (const float*)d_in[3];
    const float* qkv_w    = (const float*)d_in[4];
    const float* qkv_b    = (const float*)d_in[5];
    const float* rel_bias = (const float*)d_in[6];
    const float* proj_w   = (const float*)d_in[7];
    const float* proj_b   = (const float*)d_in[8];
    const float* n2g      = (const float*)d_in[9];
    const float* n2b      = (const float*)d_in[10];
    const float* fc1_w    = (const float*)d_in[11];
    const float* fc1_b    = (const float*)d_in[12];
    const float* fc2_w    = (const float*)d_in[13];
    const float* fc2_b    = (const float*)d_in[14];
    float* out = (float*)d_out;

    __hip_bfloat16* qkv = (__hip_bfloat16*)d_ws;                       // 154,140,672 B (dead after proj)
    float* x2 = (float*)((char*)d_ws + 154140672);                     // 102,760,448 B
    __hip_bfloat16* wb  = (__hip_bfloat16*)d_ws;                       // overlaps dead qkv region
    __hip_bfloat16* fc1_wb = wb;
    __hip_bfloat16* fc2_wb = wb + 65536;

    ln1_qkv_kernel<<<3136, 256, 0, stream>>>(x, n1g, n1b, qkv_w, qkv_b, qkv);
    attn_kernel<<<8192, 256, 0, stream>>>(qkv, mask, rel_bias);
    proj_kernel<<<3136, 256, 0, stream>>>(qkv, proj_w, proj_b, x, x2);
    prep_weights<<<512, 256, 0, stream>>>(fc1_w, fc2_w, wb);           // after proj: qkv region dead
    mlp_mfma_kernel<<<6272, 256, 0, stream>>>(x2, n2g, n2b, fc1_wb, fc2_wb, fc1_b, fc2_b, out);
}

// Round 5
// 1175.233 us; speedup vs baseline: 2.4080x; 1.5303x over previous
//
#include <hip/hip_runtime.h>
#include <hip/hip_bf16.h>

#define C_DIM 128
#define N_WIN 98
#define M_TOK 200704   // 8*8*56*56
#define B_WIN 2048

struct __align__(8) bf16x4 { __hip_bfloat16 h[4]; };

typedef __attribute__((ext_vector_type(8))) short bf16x8_t;   // 8 bf16 = 4 VGPRs
typedef __attribute__((ext_vector_type(4))) float f32x4_t;

// token index map used by BOTH gather (LN1) and scatter (proj epilogue):
// row = widx*98 + n  ->  flat spatial token index in the original layout
__device__ __forceinline__ int token_spatial_index(int row) {
    int widx = row / 98;
    int n = row - widx * 98;
    int b   = widx >> 8;          // / 256
    int rem = widx & 255;
    int dI = rem >> 6;            // D/2 = 4
    int hI = (rem >> 3) & 7;      // H/7 = 8
    int wI = rem & 7;             // W/7 = 8
    int dw = n / 49;
    int r49 = n - dw * 49;
    int hw = r49 / 7;
    int ww = r49 - hw * 7;
    int d = dI * 2 + dw;          // shifted-frame coords
    int h = hI * 7 + hw;
    int w = wI * 7 + ww;
    d = (d + 1) & 7;              // shifted[i] = orig[(i+1)%8]  (roll -1)
    h += 3; if (h >= 56) h -= 56; // roll -3
    w += 3; if (w >= 56) w -= 56;
    return ((b * 8 + d) * 56 + h) * 56 + w;
}

// ---------------- Kernel 1: LN1 + window gather + QKV GEMM ----------------
__global__ __launch_bounds__(256) void ln1_qkv_kernel(
    const float* __restrict__ x,
    const float* __restrict__ g1,
    const float* __restrict__ b1,
    const float* __restrict__ qkv_w,   // (384,128)
    const float* __restrict__ qkv_b,   // (384,)
    __hip_bfloat16* __restrict__ qkv_out)       // (200704,384) bf16 scratch
{
    __shared__ float At[128][68];   // [k][r], padded
    __shared__ float Wt[128][68];   // [k][c]
    __shared__ int   srcL[64];
    __shared__ float meanL[64], rstdL[64];

    const int tid = threadIdx.x;
    const int rowbase = blockIdx.x * 64;

    if (tid < 64) srcL[tid] = token_spatial_index(rowbase + tid);
    __syncthreads();

    #pragma unroll
    for (int i = 0; i < 32; ++i) {
        int e = tid + i * 256;
        int r = e >> 7, k = e & 127;
        At[k][r] = x[(size_t)srcL[r] * 128 + k];
    }
    __syncthreads();
    if (tid < 64) {
        float s = 0.f, ss = 0.f;
        #pragma unroll 8
        for (int k = 0; k < 128; ++k) { float v = At[k][tid]; s += v; ss += v * v; }
        float m = s * (1.f / 128.f);
        float var = ss * (1.f / 128.f) - m * m;
        meanL[tid] = m;
        rstdL[tid] = rsqrtf(var + 1e-5f);
    }
    __syncthreads();
    #pragma unroll
    for (int i = 0; i < 32; ++i) {
        int e = tid + i * 256;
        int k = e >> 6, r = e & 63;
        At[k][r] = (At[k][r] - meanL[r]) * rstdL[r] * g1[k] + b1[k];
    }
    __syncthreads();

    const int tr = tid >> 4, tc = tid & 15;
    const int tr4 = tr * 4, tc4 = tc * 4;

    for (int nt = 0; nt < 6; ++nt) {
        #pragma unroll
        for (int i = 0; i < 32; ++i) {
            int e = tid + i * 256;
            int c = e >> 7, k = e & 127;
            Wt[k][c] = qkv_w[(size_t)(nt * 64 + c) * 128 + k];
        }
        __syncthreads();
        float acc[4][4] = {};
        #pragma unroll 8
        for (int k = 0; k < 128; ++k) {
            float4 a = *(const float4*)(&At[k][tr4]);
            float4 w = *(const float4*)(&Wt[k][tc4]);
            acc[0][0] += a.x * w.x; acc[0][1] += a.x * w.y; acc[0][2] += a.x * w.z; acc[0][3] += a.x * w.w;
            acc[1][0] += a.y * w.x; acc[1][1] += a.y * w.y; acc[1][2] += a.y * w.z; acc[1][3] += a.y * w.w;
            acc[2][0] += a.z * w.x; acc[2][1] += a.z * w.y; acc[2][2] += a.z * w.z; acc[2][3] += a.z * w.w;
            acc[3][0] += a.w * w.x; acc[3][1] += a.w * w.y; acc[3][2] += a.w * w.z; acc[3][3] += a.w * w.w;
        }
        __syncthreads();
        int gcol = nt * 64 + tc4;
        float bs0 = qkv_b[gcol + 0];
        float bs1 = qkv_b[gcol + 1];
        float bs2 = qkv_b[gcol + 2];
        float bs3 = qkv_b[gcol + 3];
        #pragma unroll
        for (int i2 = 0; i2 < 4; ++i2) {
            int grow = rowbase + tr4 + i2;
            bf16x4 pk;
            pk.h[0] = __float2bfloat16(acc[i2][0] + bs0);
            pk.h[1] = __float2bfloat16(acc[i2][1] + bs1);
            pk.h[2] = __float2bfloat16(acc[i2][2] + bs2);
            pk.h[3] = __float2bfloat16(acc[i2][3] + bs3);
            *(bf16x4*)(qkv_out + (size_t)grow * 384 + gcol) = pk;
        }
    }
}

// ---------------- Kernel 2: attention per (window, head), MFMA ----------------
// QK^T: A=Q rows (M=query), B=K rows ((N,K) row-major, gemm_bt), K-dim=32 -> 1 mfma/tile.
// C/D layout (R4-verified): col=lane&15, row=quad*4+reg.
// Softmax in registers (wave owns full score rows), P -> LDS bf16 (A-layout), PV via MFMA.
// Mask computed analytically from window geometry (no mask-matrix reads).
__global__ __launch_bounds__(256) void attn_mfma_kernel(
    __hip_bfloat16* __restrict__ qkv,           // (200704,384); out overwrites q-slice
    const float* __restrict__ rel_bias)         // (507,4)
{
    __shared__ __align__(16) __hip_bfloat16 Qb[112][40];    // 8960 B (rows padded w/ zeros)
    __shared__ __align__(16) __hip_bfloat16 Kb[112][40];    // 8960 B
    __shared__ __align__(16) __hip_bfloat16 Vt[32][136];    // 8704 B (V^T, cols m padded 0 to 128)
    __shared__ __align__(16) __hip_bfloat16 Pb[112][136];   // 30464 B (probs, K pad 0 to 128)
    __shared__ float biasL[507];
    __shared__ int   idn[98];

    const int tid  = threadIdx.x;
    const int lane = tid & 63;
    const int wv   = tid >> 6;
    const int widx = blockIdx.x >> 2;
    const int head = blockIdx.x & 3;
    const int co   = head * 32;
    const size_t base = (size_t)widx * 98 * 384;

    // ---- staging ----
    bf16x8_t zz = {};
    for (int e = tid; e < 448; e += 256) {        // Q,K rows (8 bf16 per slot)
        int row = e >> 2, c8 = e & 3;
        if (row < 98) {
            size_t g = base + (size_t)row * 384;
            *(bf16x8_t*)(&Qb[row][c8 * 8]) = *(const bf16x8_t*)(qkv + g + co + c8 * 8);
            *(bf16x8_t*)(&Kb[row][c8 * 8]) = *(const bf16x8_t*)(qkv + g + 128 + co + c8 * 8);
        } else {
            *(bf16x8_t*)(&Qb[row][c8 * 8]) = zz;
            *(bf16x8_t*)(&Kb[row][c8 * 8]) = zz;
        }
    }
    for (int e = tid; e < 448; e += 256) {        // V -> Vt transpose scatter
        int row = e >> 2, c8 = e & 3;
        if (row < 98) {
            bf16x8_t v = *(const bf16x8_t*)(qkv + base + (size_t)row * 384 + 256 + co + c8 * 8);
            #pragma unroll
            for (int j = 0; j < 8; ++j) Vt[c8 * 8 + j][row] = ((__hip_bfloat16*)&v)[j];
        }
    }
    for (int e = tid; e < 1024; e += 256) {       // Vt zero pad m in [98,128)
        int r = e >> 5, c = 96 + (e & 31);
        if (c >= 98) Vt[r][c] = __float2bfloat16(0.f);
    }
    for (int e = tid; e < 1792; e += 256) {       // Pb zero pad k in [112,128)
        int r = e >> 4, c = 112 + (e & 15);
        Pb[r][c] = __float2bfloat16(0.f);
    }
    for (int i = tid; i < 507; i += 256) biasL[i] = rel_bias[i * 4 + head];
    if (tid < 98) {                               // region id (compute_mask analytic form)
        int wloc = widx & 255;
        int dI = wloc >> 6, hI = (wloc >> 3) & 7, wI = wloc & 7;
        int n = tid;
        int dw = n / 49, r49 = n - dw * 49, hw = r49 / 7, ww2 = r49 - hw * 7;
        int d = dI * 2 + dw, h = hI * 7 + hw, w = wI * 7 + ww2;
        int di = (d < 6) ? 0 : (d < 7 ? 1 : 2);
        int hi = (h < 49) ? 0 : (h < 52 ? 1 : 2);
        int wi = (w < 49) ? 0 : (w < 52 ? 1 : 2);
        idn[n] = di * 9 + hi * 3 + wi;
    }
    __syncthreads();

    const int lm = lane & 15, quad = lane >> 4;
    const float scale = 0.17677669529663687f;     // 32^-0.5

    // ---- QK^T + bias + mask + softmax (wave owns row-tiles wv, wv+4) ----
    for (int tM = wv; tM < 7; tM += 4) {
        bf16x8_t afr = *(const bf16x8_t*)(&Qb[tM * 16 + lm][quad * 8]);
        f32x4_t acc[7];
        #pragma unroll
        for (int tN = 0; tN < 7; ++tN) {
            bf16x8_t bfr = *(const bf16x8_t*)(&Kb[tN * 16 + lm][quad * 8]);
            f32x4_t c0 = {0.f, 0.f, 0.f, 0.f};
            acc[tN] = __builtin_amdgcn_mfma_f32_16x16x32_bf16(afr, bfr, c0, 0, 0, 0);
        }
        float sv[7][4];
        #pragma unroll
        for (int tN = 0; tN < 7; ++tN) {
            int m = tN * 16 + lm;
            #pragma unroll
            for (int rg = 0; rg < 4; ++rg) {
                int n = tM * 16 + quad * 4 + rg;
                float s;
                if (n < 98 && m < 98) {
                    int d1 = n / 49, r1 = n - d1 * 49, h1 = r1 / 7, w1 = r1 - h1 * 7;
                    int d2 = m / 49, r2 = m - d2 * 49, h2 = r2 / 7, w2 = r2 - h2 * 7;
                    int bidx = (d1 - d2 + 1) * 169 + (h1 - h2 + 6) * 13 + (w1 - w2 + 6);
                    s = acc[tN][rg] * scale + biasL[bidx];
                    s += (idn[n] == idn[m]) ? 0.f : -100.f;
                } else {
                    s = -1e30f;
                }
                sv[tN][rg] = s;
            }
        }
        #pragma unroll
        for (int rg = 0; rg < 4; ++rg) {
            float mx = sv[0][rg];
            #pragma unroll
            for (int tN = 1; tN < 7; ++tN) mx = fmaxf(mx, sv[tN][rg]);
            mx = fmaxf(mx, __shfl_xor(mx, 1));
            mx = fmaxf(mx, __shfl_xor(mx, 2));
            mx = fmaxf(mx, __shfl_xor(mx, 4));
            mx = fmaxf(mx, __shfl_xor(mx, 8));
            float p[7], sum = 0.f;
            #pragma unroll
            for (int tN = 0; tN < 7; ++tN) { p[tN] = __expf(sv[tN][rg] - mx); sum += p[tN]; }
            sum += __shfl_xor(sum, 1);
            sum += __shfl_xor(sum, 2);
            sum += __shfl_xor(sum, 4);
            sum += __shfl_xor(sum, 8);
            float inv = 1.f / sum;
            int n = tM * 16 + quad * 4 + rg;
            #pragma unroll
            for (int tN = 0; tN < 7; ++tN)
                Pb[n][tN * 16 + lm] = __float2bfloat16(p[tN] * inv);
        }
    }
    __syncthreads();

    // ---- PV: out[n][c] = sum_m P[n][m] * V[m][c], K=128 (padded) ----
    for (int t = wv; t < 14; t += 4) {
        int tM = t >> 1, tN = t & 1;
        f32x4_t acc = {0.f, 0.f, 0.f, 0.f};
        #pragma unroll
        for (int s = 0; s < 4; ++s) {
            bf16x8_t afr = *(const bf16x8_t*)(&Pb[tM * 16 + lm][s * 32 + quad * 8]);
            bf16x8_t bfr = *(const bf16x8_t*)(&Vt[tN * 16 + lm][s * 32 + quad * 8]);
            acc = __builtin_amdgcn_mfma_f32_16x16x32_bf16(afr, bfr, acc, 0, 0, 0);
        }
        int m = tN * 16 + lm;
        #pragma unroll
        for (int rg = 0; rg < 4; ++rg) {
            int n = tM * 16 + quad * 4 + rg;
            if (n < 98)
                qkv[base + (size_t)n * 384 + co + m] = __float2bfloat16(acc[rg]);  // q-slice reuse
        }
    }
}

// ---------------- Kernel 3: proj GEMM + window-reverse scatter + residual ----------------
__global__ __launch_bounds__(256) void proj_kernel(
    const __hip_bfloat16* __restrict__ attn,    // qkv buffer, cols 0..127 hold attn out
    const float* __restrict__ proj_w,           // (128,128)
    const float* __restrict__ proj_b,
    const float* __restrict__ x,
    float* __restrict__ x2)
{
    __shared__ float At[128][68];
    __shared__ float Wt[128][68];
    __shared__ int dstL[64];

    const int tid = threadIdx.x;
    const int rowbase = blockIdx.x * 64;
    if (tid < 64) dstL[tid] = token_spatial_index(rowbase + tid);
    __syncthreads();

    #pragma unroll
    for (int i = 0; i < 32; ++i) {
        int e = tid + i * 256;
        int r = e >> 7, k = e & 127;
        At[k][r] = __bfloat162float(attn[(size_t)(rowbase + r) * 384 + k]);
    }

    const int tr = tid >> 4, tc = tid & 15;
    const int tr4 = tr * 4, tc4 = tc * 4;

    for (int nt = 0; nt < 2; ++nt) {
        #pragma unroll
        for (int i = 0; i < 32; ++i) {
            int e = tid + i * 256;
            int c = e >> 7, k = e & 127;
            Wt[k][c] = proj_w[(size_t)(nt * 64 + c) * 128 + k];
        }
        __syncthreads();
        float acc[4][4] = {};
        #pragma unroll 8
        for (int k = 0; k < 128; ++k) {
            float4 a = *(const float4*)(&At[k][tr4]);
            float4 w = *(const float4*)(&Wt[k][tc4]);
            acc[0][0] += a.x * w.x; acc[0][1] += a.x * w.y; acc[0][2] += a.x * w.z; acc[0][3] += a.x * w.w;
            acc[1][0] += a.y * w.x; acc[1][1] += a.y * w.y; acc[1][2] += a.y * w.z; acc[1][3] += a.y * w.w;
            acc[2][0] += a.z * w.x; acc[2][1] += a.z * w.y; acc[2][2] += a.z * w.z; acc[2][3] += a.z * w.w;
            acc[3][0] += a.w * w.x; acc[3][1] += a.w * w.y; acc[3][2] += a.w * w.z; acc[3][3] += a.w * w.w;
        }
        __syncthreads();
        int gcol = nt * 64 + tc4;
        float bs0 = proj_b[gcol + 0];
        float bs1 = proj_b[gcol + 1];
        float bs2 = proj_b[gcol + 2];
        float bs3 = proj_b[gcol + 3];
        #pragma unroll
        for (int i2 = 0; i2 < 4; ++i2) {
            int dst = dstL[tr4 + i2];
            size_t off = (size_t)dst * 128 + gcol;
            float4 xr = *(const float4*)(x + off);
            float4 res;
            res.x = acc[i2][0] + bs0 + xr.x;
            res.y = acc[i2][1] + bs1 + xr.y;
            res.z = acc[i2][2] + bs2 + xr.z;
            res.w = acc[i2][3] + bs3 + xr.w;
            *(float4*)(x2 + off) = res;
        }
    }
}

// ---------------- Kernel 3.5: convert MLP weights fp32 -> bf16 (into dead qkv region) ----------------
__global__ __launch_bounds__(256) void prep_weights(
    const float* __restrict__ fc1_w,   // (512,128) = 65536
    const float* __restrict__ fc2_w,   // (128,512) = 65536
    __hip_bfloat16* __restrict__ wb)   // [0..65535]=fc1, [65536..131071]=fc2
{
    int i = blockIdx.x * 256 + threadIdx.x;
    if (i < 65536)       wb[i] = __float2bfloat16(fc1_w[i]);
    else if (i < 131072) wb[i] = __float2bfloat16(fc2_w[i - 65536]);
}

// ---------------- Kernel 4: LN2 + fc1 + GELU + fc2 + residual (MFMA) ----------------
__global__ __launch_bounds__(256) void mlp_mfma_kernel(
    const float* __restrict__ x2,
    const float* __restrict__ g2,
    const float* __restrict__ b2,
    const __hip_bfloat16* __restrict__ fc1_wb,  // (512,128) bf16
    const __hip_bfloat16* __restrict__ fc2_wb,  // (128,512) bf16
    const float* __restrict__ fc1_b,
    const float* __restrict__ fc2_b,
    float* __restrict__ out)
{
    __shared__ float raw[32][132];                         // 16896 B (residual + LN input)
    __shared__ __align__(16) __hip_bfloat16 Abf[32][136];  // 8704 B  (LN output, bf16)
    __shared__ __align__(16) __hip_bfloat16 Hbf[32][520];  // 33280 B (hidden, bf16)
    __shared__ float meanL[32], rstdL[32];

    const int tid  = threadIdx.x;
    const int lane = tid & 63;
    const int wv   = tid >> 6;
    const int rowbase = blockIdx.x * 32;

    #pragma unroll
    for (int i = 0; i < 4; ++i) {
        int idx = tid + i * 256;
        int r = idx >> 5, c4 = idx & 31;
        float4 v = *(const float4*)(x2 + (size_t)(rowbase + r) * 128 + c4 * 4);
        *(float4*)(&raw[r][c4 * 4]) = v;
    }
    __syncthreads();

    {
        int r = tid >> 3, part = tid & 7;
        float s = 0.f, ss = 0.f;
        #pragma unroll
        for (int j = 0; j < 16; ++j) {
            float v = raw[r][part * 16 + j];
            s += v; ss += v * v;
        }
        s  += __shfl_xor(s, 1);  ss += __shfl_xor(ss, 1);
        s  += __shfl_xor(s, 2);  ss += __shfl_xor(ss, 2);
        s  += __shfl_xor(s, 4);  ss += __shfl_xor(ss, 4);
        if (part == 0) {
            float m = s * (1.f / 128.f);
            float var = ss * (1.f / 128.f) - m * m;
            meanL[r] = m;
            rstdL[r] = rsqrtf(var + 1e-5f);
        }
    }
    __syncthreads();

    #pragma unroll
    for (int i = 0; i < 16; ++i) {
        int e = tid + i * 256;
        int r = e >> 7, k = e & 127;
        float v = (raw[r][k] - meanL[r]) * rstdL[r] * g2[k] + b2[k];
        Abf[r][k] = __float2bfloat16(v);
    }
    __syncthreads();

    const int rw    = (wv & 1) * 16;
    const int chalf = (wv >> 1) * 256;
    const int lm    = lane & 15;
    const int quad  = lane >> 4;

    {
        bf16x8_t afr[4];
        #pragma unroll
        for (int s = 0; s < 4; ++s)
            afr[s] = *(const bf16x8_t*)(&Abf[rw + lm][s * 32 + quad * 8]);

        for (int ct = 0; ct < 16; ++ct) {
            int ccol = chalf + ct * 16 + lm;
            const __hip_bfloat16* wp = fc1_wb + (size_t)ccol * 128 + quad * 8;
            f32x4_t acc = {0.f, 0.f, 0.f, 0.f};
            #pragma unroll
            for (int s = 0; s < 4; ++s) {
                bf16x8_t bfr = *(const bf16x8_t*)(wp + s * 32);
                acc = __builtin_amdgcn_mfma_f32_16x16x32_bf16(afr[s], bfr, acc, 0, 0, 0);
            }
            float bb = fc1_b[ccol];
            #pragma unroll
            for (int rg = 0; rg < 4; ++rg) {
                float v = acc[rg] + bb;
                v = 0.5f * v * (1.f + erff(v * 0.70710678118654752f));
                Hbf[rw + quad * 4 + rg][ccol] = __float2bfloat16(v);
            }
        }
    }
    __syncthreads();

    {
        const int cq = (wv >> 1) * 64;
        bf16x8_t hfr[16];
        #pragma unroll
        for (int s = 0; s < 16; ++s)
            hfr[s] = *(const bf16x8_t*)(&Hbf[rw + lm][s * 32 + quad * 8]);

        #pragma unroll
        for (int ct = 0; ct < 4; ++ct) {
            int ccol = cq + ct * 16 + lm;
            const __hip_bfloat16* wp = fc2_wb + (size_t)ccol * 512 + quad * 8;
            f32x4_t acc = {0.f, 0.f, 0.f, 0.f};
            #pragma unroll
            for (int s = 0; s < 16; ++s) {
                bf16x8_t bfr = *(const bf16x8_t*)(wp + s * 32);
                acc = __builtin_amdgcn_mfma_f32_16x16x32_bf16(hfr[s], bfr, acc, 0, 0, 0);
            }
            float bb = fc2_b[ccol];
            #pragma unroll
            for (int rg = 0; rg < 4; ++rg) {
                int rr = rw + quad * 4 + rg;
                out[(size_t)(rowbase + rr) * 128 + ccol] = acc[rg] + bb + raw[rr][ccol];
            }
        }
    }
}

extern "C" void kernel_launch(void* const* d_in, const int* in_sizes, int n_in,
                              void* d_out, int out_size, void* d_ws, size_t ws_size,
                              hipStream_t stream) {
    const float* x        = (const float*)d_in[0];
    const float* n1g      = (const float*)d_in[2];
    const float* n1b      = (const float*)d_in[3];
    const float* qkv_w    = (const float*)d_in[4];
    const float* qkv_b    = (const float*)d_in[5];
    const float* rel_bias = (const float*)d_in[6];
    const float* proj_w   = (const float*)d_in[7];
    const float* proj_b   = (const float*)d_in[8];
    const float* n2g      = (const float*)d_in[9];
    const float* n2b      = (const float*)d_in[10];
    const float* fc1_w    = (const float*)d_in[11];
    const float* fc1_b    = (const float*)d_in[12];
    const float* fc2_w    = (const float*)d_in[13];
    const float* fc2_b    = (const float*)d_in[14];
    float* out = (float*)d_out;

    __hip_bfloat16* qkv = (__hip_bfloat16*)d_ws;                       // 154,140,672 B (dead after proj)
    float* x2 = (float*)((char*)d_ws + 154140672);                     // 102,760,448 B
    __hip_bfloat16* wb  = (__hip_bfloat16*)d_ws;                       // overlaps dead qkv region
    __hip_bfloat16* fc1_wb = wb;
    __hip_bfloat16* fc2_wb = wb + 65536;

    ln1_qkv_kernel<<<3136, 256, 0, stream>>>(x, n1g, n1b, qkv_w, qkv_b, qkv);
    attn_mfma_kernel<<<8192, 256, 0, stream>>>(qkv, rel_bias);
    proj_kernel<<<3136, 256, 0, stream>>>(qkv, proj_w, proj_b, x, x2);
    prep_weights<<<512, 256, 0, stream>>>(fc1_w, fc2_w, wb);           // after proj: qkv region dead
    mlp_mfma_kernel<<<6272, 256, 0, stream>>>(x2, n2g, n2b, fc1_wb, fc2_wb, fc1_b, fc2_b, out);
}